// Round 1
// baseline (4442.027 us; speedup 1.0000x reference)
//
#include <hip/hip_runtime.h>
#include <math.h>

// ---------------------------------------------------------------------------
// SGConv net: K=3 hop propagation (gcn_norm w/ self loops) -> linear ->
// global mean pool -> MLP head -> log_softmax.
// Sizes: N=100000, E=1600000, F_IN=64, H=64, C=10, G=512 (taken from in_sizes
// at runtime where possible; F/H/C fixed by the model).
// ---------------------------------------------------------------------------

#define F 64   // F_IN == H == 64
#define NC 10  // classes

// deg[i] = 1 (self loop); zero graph sums/counts
__global__ void k_init(float* deg, float* gsum, float* gcnt, int n, int g) {
    int i = blockIdx.x * blockDim.x + threadIdx.x;
    if (i < n) deg[i] = 1.0f;
    if (i < g * F) gsum[i] = 0.0f;
    if (i < g) gcnt[i] = 0.0f;
}

__global__ void k_deg(const int* col, const float* ew, float* deg, int e) {
    int i = blockIdx.x * blockDim.x + threadIdx.x;
    if (i < e) atomicAdd(&deg[col[i]], ew[i]);
}

__global__ void k_dinv(float* deg, int n) {
    int i = blockIdx.x * blockDim.x + threadIdx.x;
    if (i < n) {
        float d = deg[i];
        deg[i] = (d > 0.0f) ? rsqrtf(d) : 0.0f;
    }
}

// out[i] = dinv[i]^2 * in[i]  (self-loop term; also initializes out)
__global__ void k_self(const float* __restrict__ in, const float* __restrict__ dinv,
                       float* __restrict__ out, int n) {
    int t = blockIdx.x * blockDim.x + threadIdx.x;
    if (t >= n * (F / 4)) return;
    int i = t >> 4, k = t & 15;
    float s = dinv[i];
    s *= s;
    float4 v = ((const float4*)in)[i * 16 + k];
    v.x *= s; v.y *= s; v.z *= s; v.w *= s;
    ((float4*)out)[i * 16 + k] = v;
}

// out[col] += dinv[row]*ew*dinv[col] * in[row]; 16 threads/edge, float4 each
__global__ void k_edge(const int* __restrict__ row, const int* __restrict__ col,
                       const float* __restrict__ ew, const float* __restrict__ dinv,
                       const float* __restrict__ in, float* __restrict__ out, int e) {
    int t = blockIdx.x * blockDim.x + threadIdx.x;
    if (t >= e * 16) return;
    int ed = t >> 4, k = t & 15;
    int r = row[ed], c = col[ed];
    float coef = dinv[r] * ew[ed] * dinv[c];
    float4 v = ((const float4*)in)[r * 16 + k];
    float* o = out + c * F + k * 4;
    atomicAdd(o + 0, coef * v.x);
    atomicAdd(o + 1, coef * v.y);
    atomicAdd(o + 2, coef * v.z);
    atomicAdd(o + 3, coef * v.w);
}

// y = h @ conv_w + conv_b, then atomic mean-pool accumulate per graph
__global__ void k_conv_pool(const float* __restrict__ h, const float* __restrict__ w,
                            const float* __restrict__ b, const int* __restrict__ batch,
                            float* __restrict__ gsum, float* __restrict__ gcnt, int n) {
    __shared__ float ws[F * F];
    __shared__ float hs[4][F];
    for (int i = threadIdx.x; i < F * F; i += blockDim.x) ws[i] = w[i];
    __syncthreads();
    int c = threadIdx.x & (F - 1);
    int rl = threadIdx.x >> 6;  // 0..3
    float bc = b[c];
    for (int r0 = blockIdx.x * 4; r0 < n; r0 += gridDim.x * 4) {
        int r = r0 + rl;
        if (r < n) hs[rl][c] = h[r * F + c];
        __syncthreads();
        if (r < n) {
            float acc = bc;
#pragma unroll
            for (int k = 0; k < F; k++) acc += hs[rl][k] * ws[k * F + c];
            int g = batch[r];
            atomicAdd(&gsum[g * F + c], acc);
            if (c == 0) atomicAdd(&gcnt[g], 1.0f);
        }
        __syncthreads();
    }
}

// per-graph MLP head + log_softmax. 1 block (64 threads) per graph.
__global__ void k_head(const float* __restrict__ gsum, const float* __restrict__ gcnt,
                       const float* __restrict__ w1, const float* __restrict__ b1,
                       const float* __restrict__ w2, const float* __restrict__ b2,
                       float* __restrict__ out) {
    __shared__ float gm[F], hid[F], lg[NC];
    int g = blockIdx.x, c = threadIdx.x;
    float cnt = fmaxf(gcnt[g], 1.0f);
    gm[c] = gsum[g * F + c] / cnt;
    __syncthreads();
    float a = b1[c];
#pragma unroll
    for (int k = 0; k < F; k++) a += gm[k] * w1[k * F + c];
    hid[c] = fmaxf(a, 0.0f);
    __syncthreads();
    if (c < NC) {
        float a2 = b2[c];
#pragma unroll
        for (int k = 0; k < F; k++) a2 += hid[k] * w2[k * NC + c];
        lg[c] = a2;
    }
    __syncthreads();
    if (c < NC) {
        float m = lg[0];
#pragma unroll
        for (int j = 1; j < NC; j++) m = fmaxf(m, lg[j]);
        float s = 0.0f;
#pragma unroll
        for (int j = 0; j < NC; j++) s += expf(lg[j] - m);
        out[g * NC + c] = lg[c] - m - logf(s);
    }
}

static inline size_t align256(size_t x) { return (x + 255) & ~(size_t)255; }

extern "C" void kernel_launch(void* const* d_in, const int* in_sizes, int n_in,
                              void* d_out, int out_size, void* d_ws, size_t ws_size,
                              hipStream_t stream) {
    const float* x       = (const float*)d_in[0];
    const int*   eidx    = (const int*)d_in[1];
    const float* ew      = (const float*)d_in[2];
    const int*   batch   = (const int*)d_in[3];
    const float* conv_w  = (const float*)d_in[4];
    const float* conv_b  = (const float*)d_in[5];
    const float* lin1_w  = (const float*)d_in[6];
    const float* lin1_b  = (const float*)d_in[7];
    const float* lin2_w  = (const float*)d_in[8];
    const float* lin2_b  = (const float*)d_in[9];
    float* out = (float*)d_out;

    const int n = in_sizes[0] / F;        // 100000
    const int e = in_sizes[2];            // 1600000
    const int g = out_size / NC;          // 512
    const int* row = eidx;                // edge_index[0]
    const int* col = eidx + e;            // edge_index[1]

    // workspace carve-up
    char* ws = (char*)d_ws;
    size_t off = 0;
    float* dinv = (float*)(ws + off); off = align256(off + (size_t)n * 4);
    float* hA   = (float*)(ws + off); off = align256(off + (size_t)n * F * 4);
    float* hB   = (float*)(ws + off); off = align256(off + (size_t)n * F * 4);
    float* gsum = (float*)(ws + off); off = align256(off + (size_t)g * F * 4);
    float* gcnt = (float*)(ws + off); off = align256(off + (size_t)g * 4);
    (void)ws_size;

    const int B = 256;
    // 1) degree (self loop = 1) + zero pool buffers
    k_init<<<(n + B - 1) / B, B, 0, stream>>>(dinv, gsum, gcnt, n, g);
    k_deg<<<(e + B - 1) / B, B, 0, stream>>>(col, ew, dinv, e);
    k_dinv<<<(n + B - 1) / B, B, 0, stream>>>(dinv, n);

    // 2) K = 3 hops: x -> hA -> hB -> hA
    const float* src = x;
    float* dst = hA;
    for (int hop = 0; hop < 3; hop++) {
        int tSelf = n * (F / 4);
        k_self<<<(tSelf + B - 1) / B, B, 0, stream>>>(src, dinv, dst, n);
        int tEdge = e * 16;
        k_edge<<<(tEdge + B - 1) / B, B, 0, stream>>>(row, col, ew, dinv, src, dst, e);
        src = dst;
        dst = (dst == hA) ? hB : hA;
    }
    // after 3 hops result is in hB (x->hA->hB->hA? trace: hop0 dst=hA, hop1 dst=hB, hop2 dst=hA)
    const float* hfin = src;  // src points at the last dst

    // 3) conv + mean-pool accumulate
    k_conv_pool<<<2048, 256, 0, stream>>>(hfin, conv_w, conv_b, batch, gsum, gcnt, n);

    // 4) head
    k_head<<<g, F, 0, stream>>>(gsum, gcnt, lin1_w, lin1_b, lin2_w, lin2_b, out);
}

// Round 2
// 707.439 us; speedup vs baseline: 6.2790x; 6.2790x over previous
//
#include <hip/hip_runtime.h>
#include <math.h>

// ---------------------------------------------------------------------------
// SGConv: gcn_norm + K=3 pull-mode propagation over on-device CSR (sorted by
// destination), then linear -> mean pool -> MLP -> log_softmax.
// N=100000, E=1600000, F=64, C=10, G=512.
// ---------------------------------------------------------------------------

#define F 64
#define NC 10

// deg=1 (self loop), cnt=0, gsum=0, gcnt=0
__global__ void k_init(float* deg, int* cnt, float* gsum, float* gcnt, int n, int g) {
    int i = blockIdx.x * blockDim.x + threadIdx.x;
    if (i < n) { deg[i] = 1.0f; cnt[i] = 0; }
    if (i < g * F) gsum[i] = 0.0f;
    if (i < g) gcnt[i] = 0.0f;
}

// degree sum (float) + in-degree count (int)
__global__ void k_deg(const int* __restrict__ col, const float* __restrict__ ew,
                      float* __restrict__ deg, int* __restrict__ cnt, int e) {
    int i = blockIdx.x * blockDim.x + threadIdx.x;
    if (i < e) {
        int c = col[i];
        atomicAdd(&deg[c], ew[i]);
        atomicAdd(&cnt[c], 1);
    }
}

__global__ void k_dinv(float* deg, int n) {
    int i = blockIdx.x * blockDim.x + threadIdx.x;
    if (i < n) {
        float d = deg[i];
        deg[i] = (d > 0.0f) ? rsqrtf(d) : 0.0f;
    }
}

// ---- exclusive scan of cnt[n] -> rpt[n] (3-kernel scan) ----
__global__ void k_scan1(const int* __restrict__ cnt, int* __restrict__ rpt,
                        int* __restrict__ bsum, int n) {
    __shared__ int s[256];
    int i = blockIdx.x * 256 + threadIdx.x;
    int v = (i < n) ? cnt[i] : 0;
    s[threadIdx.x] = v;
    __syncthreads();
    for (int off = 1; off < 256; off <<= 1) {
        int t = (threadIdx.x >= off) ? s[threadIdx.x - off] : 0;
        __syncthreads();
        s[threadIdx.x] += t;
        __syncthreads();
    }
    if (i < n) rpt[i] = s[threadIdx.x] - v;  // exclusive within block
    if (threadIdx.x == 255) bsum[blockIdx.x] = s[255];
}

__global__ void k_scan2(int* bsum, int nb) {
    __shared__ int s[256];
    __shared__ int carry;
    if (threadIdx.x == 0) carry = 0;
    __syncthreads();
    for (int base = 0; base < nb; base += 256) {
        int i = base + threadIdx.x;
        int v = (i < nb) ? bsum[i] : 0;
        s[threadIdx.x] = v;
        __syncthreads();
        for (int off = 1; off < 256; off <<= 1) {
            int t = (threadIdx.x >= off) ? s[threadIdx.x - off] : 0;
            __syncthreads();
            s[threadIdx.x] += t;
            __syncthreads();
        }
        if (i < nb) bsum[i] = s[threadIdx.x] - v + carry;
        int tot = s[255];
        __syncthreads();
        if (threadIdx.x == 0) carry += tot;
        __syncthreads();
    }
}

// rpt[i] += bsum[i>>8]; cursor[i] = rpt[i]; rpt[n] = e
__global__ void k_scan3(int* __restrict__ rpt, const int* __restrict__ bsum,
                        int* __restrict__ cursor, int n, int e) {
    int i = blockIdx.x * blockDim.x + threadIdx.x;
    if (i < n) {
        int v = rpt[i] + bsum[i >> 8];
        rpt[i] = v;
        cursor[i] = v;
    }
    if (i == 0) rpt[n] = e;
}

// scatter edge records (row, coef) into CSR slots by destination
__global__ void k_fill(const int* __restrict__ row, const int* __restrict__ col,
                       const float* __restrict__ ew, const float* __restrict__ dinv,
                       int* __restrict__ cursor, int2* __restrict__ edata, int e) {
    int i = blockIdx.x * blockDim.x + threadIdx.x;
    if (i < e) {
        int r = row[i], c = col[i];
        float coef = dinv[r] * ew[i] * dinv[c];
        int pos = atomicAdd(&cursor[c], 1);
        edata[pos] = make_int2(r, __float_as_int(coef));
    }
}

// pull-mode hop: 16 threads per node, float4 feature slot each.
// acc starts at dinv^2 * in[node] (self loop), then += coef * in[row].
__global__ void k_hop(const int2* __restrict__ edata, const int* __restrict__ rpt,
                      const float* __restrict__ dinv, const float* __restrict__ in,
                      float* __restrict__ out, int n) {
    int t = blockIdx.x * blockDim.x + threadIdx.x;
    int node = t >> 4, k = t & 15;
    if (node >= n) return;
    const float4* in4 = (const float4*)in;
    float s = dinv[node];
    s *= s;
    float4 acc = in4[node * 16 + k];
    acc.x *= s; acc.y *= s; acc.z *= s; acc.w *= s;
    int st = rpt[node], en = rpt[node + 1];
    for (int j = st; j < en; j++) {
        int2 ed = edata[j];
        float coef = __int_as_float(ed.y);
        float4 v = in4[ed.x * 16 + k];
        acc.x += coef * v.x; acc.y += coef * v.y;
        acc.z += coef * v.z; acc.w += coef * v.w;
    }
    ((float4*)out)[node * 16 + k] = acc;
}

// y = h @ conv_w + conv_b, then atomic mean-pool accumulate per graph
__global__ void k_conv_pool(const float* __restrict__ h, const float* __restrict__ w,
                            const float* __restrict__ b, const int* __restrict__ batch,
                            float* __restrict__ gsum, float* __restrict__ gcnt, int n) {
    __shared__ float ws[F * F];
    __shared__ float hs[4][F];
    for (int i = threadIdx.x; i < F * F; i += blockDim.x) ws[i] = w[i];
    __syncthreads();
    int c = threadIdx.x & (F - 1);
    int rl = threadIdx.x >> 6;
    float bc = b[c];
    for (int r0 = blockIdx.x * 4; r0 < n; r0 += gridDim.x * 4) {
        int r = r0 + rl;
        if (r < n) hs[rl][c] = h[r * F + c];
        __syncthreads();
        if (r < n) {
            float acc = bc;
#pragma unroll
            for (int k = 0; k < F; k++) acc += hs[rl][k] * ws[k * F + c];
            int g = batch[r];
            atomicAdd(&gsum[g * F + c], acc);
            if (c == 0) atomicAdd(&gcnt[g], 1.0f);
        }
        __syncthreads();
    }
}

// per-graph MLP head + log_softmax
__global__ void k_head(const float* __restrict__ gsum, const float* __restrict__ gcnt,
                       const float* __restrict__ w1, const float* __restrict__ b1,
                       const float* __restrict__ w2, const float* __restrict__ b2,
                       float* __restrict__ out) {
    __shared__ float gm[F], hid[F], lg[NC];
    int g = blockIdx.x, c = threadIdx.x;
    float cnt = fmaxf(gcnt[g], 1.0f);
    gm[c] = gsum[g * F + c] / cnt;
    __syncthreads();
    float a = b1[c];
#pragma unroll
    for (int k = 0; k < F; k++) a += gm[k] * w1[k * F + c];
    hid[c] = fmaxf(a, 0.0f);
    __syncthreads();
    if (c < NC) {
        float a2 = b2[c];
#pragma unroll
        for (int k = 0; k < F; k++) a2 += hid[k] * w2[k * NC + c];
        lg[c] = a2;
    }
    __syncthreads();
    if (c < NC) {
        float m = lg[0];
#pragma unroll
        for (int j = 1; j < NC; j++) m = fmaxf(m, lg[j]);
        float s = 0.0f;
#pragma unroll
        for (int j = 0; j < NC; j++) s += expf(lg[j] - m);
        out[g * NC + c] = lg[c] - m - logf(s);
    }
}

static inline size_t align256(size_t x) { return (x + 255) & ~(size_t)255; }

extern "C" void kernel_launch(void* const* d_in, const int* in_sizes, int n_in,
                              void* d_out, int out_size, void* d_ws, size_t ws_size,
                              hipStream_t stream) {
    const float* x      = (const float*)d_in[0];
    const int*   eidx   = (const int*)d_in[1];
    const float* ew     = (const float*)d_in[2];
    const int*   batch  = (const int*)d_in[3];
    const float* conv_w = (const float*)d_in[4];
    const float* conv_b = (const float*)d_in[5];
    const float* lin1_w = (const float*)d_in[6];
    const float* lin1_b = (const float*)d_in[7];
    const float* lin2_w = (const float*)d_in[8];
    const float* lin2_b = (const float*)d_in[9];
    float* out = (float*)d_out;

    const int n = in_sizes[0] / F;  // 100000
    const int e = in_sizes[2];      // 1600000
    const int g = out_size / NC;    // 512
    const int* row = eidx;
    const int* col = eidx + e;
    const int nb = (n + 255) / 256;

    // workspace carve-up
    char* ws = (char*)d_ws;
    size_t off = 0;
    float* dinv  = (float*)(ws + off); off = align256(off + (size_t)n * 4);
    int*   cnt   = (int*)(ws + off);   off = align256(off + (size_t)n * 4);   // reused as cursor
    int*   rpt   = (int*)(ws + off);   off = align256(off + (size_t)(n + 1) * 4);
    int*   bsum  = (int*)(ws + off);   off = align256(off + (size_t)nb * 4);
    int2*  edata = (int2*)(ws + off);  off = align256(off + (size_t)e * 8);
    float* hA    = (float*)(ws + off); off = align256(off + (size_t)n * F * 4);
    float* hB    = (float*)(ws + off); off = align256(off + (size_t)n * F * 4);
    float* gsum  = (float*)(ws + off); off = align256(off + (size_t)g * F * 4);
    float* gcnt  = (float*)(ws + off); off = align256(off + (size_t)g * 4);
    (void)ws_size;

    const int B = 256;
    int initN = (g * F > n) ? g * F : n;

    // 1) norm + CSR build
    k_init<<<(initN + B - 1) / B, B, 0, stream>>>(dinv, cnt, gsum, gcnt, n, g);
    k_deg<<<(e + B - 1) / B, B, 0, stream>>>(col, ew, dinv, cnt, e);
    k_dinv<<<(n + B - 1) / B, B, 0, stream>>>(dinv, n);
    k_scan1<<<nb, 256, 0, stream>>>(cnt, rpt, bsum, n);
    k_scan2<<<1, 256, 0, stream>>>(bsum, nb);
    k_scan3<<<nb, 256, 0, stream>>>(rpt, bsum, cnt, n, e);
    k_fill<<<(e + B - 1) / B, B, 0, stream>>>(row, col, ew, dinv, cnt, edata, e);

    // 2) K = 3 gather hops: x -> hA -> hB -> hA
    const float* src = x;
    float* dst = hA;
    for (int hop = 0; hop < 3; hop++) {
        int t = n * 16;
        k_hop<<<(t + B - 1) / B, B, 0, stream>>>(edata, rpt, dinv, src, dst, n);
        src = dst;
        dst = (dst == hA) ? hB : hA;
    }

    // 3) conv + mean-pool accumulate
    k_conv_pool<<<2048, 256, 0, stream>>>(src, conv_w, conv_b, batch, gsum, gcnt, n);

    // 4) head
    k_head<<<g, F, 0, stream>>>(gsum, gcnt, lin1_w, lin1_b, lin2_w, lin2_b, out);
}